// Round 11
// baseline (178.599 us; speedup 1.0000x reference)
//
#include <hip/hip_runtime.h>
#include <math.h>

// DecoderCell fused kernel — Round 11: R9 base (RT=128/NT=512, rcp diet) with
// all GEMMs moved to mfma_f32_32x32x16_bf16. 32-wide col-tiles cut LDS
// A-fragment reads ~6x (ph2: 2688->448 reads/CU) — R9's dominant pipe cost.
// Jobs: con 8 (4 ct x 2 rh), gen 14 (7 ct x 2 rh), factor 8 (2 ct x 4 rt).
// W3/W4 padded to 640 rows (B-row index reaches 400+223=623).

#define NT 512
#define RT 128
#define XD 272
#define HD 420

typedef unsigned short ushort_t;
typedef __attribute__((ext_vector_type(8))) short bf8;
typedef __attribute__((ext_vector_type(4))) float f4;
typedef __attribute__((ext_vector_type(16))) float f16v;
typedef __attribute__((ext_vector_type(4))) unsigned short us4;

// ws layout (bf16 element offsets)
#define WS_W1 0         // con_w_ih [384][320]
#define WS_W2 122880    // con_w_hh [384][128]
#define WS_W3 172032    // gen_w_ih [640][32]  (K 20->32 pad, rows 600-639 zero)
#define WS_W4 192512    // gen_w_hh [640][224] (K 200->224 pad, rows 600-639 zero)
#define WS_W5 335872    // normed fac_w [64][224] (K pad zero)

#define STA 328
#define STG 216
#define STH 136
#define STR3 88

#define O_A   0        // sA [128][328] = 83,968 ; later sGo [128][216]=55,296
#define O_GN  55296    // sGn [128][216] = 55,296
#define O_R2  83968    // sR2 [128][136] = 34,816
#define O_R3  118784   // sR3 [128][88]  = 22,528
#define POOLB 141312

__device__ __forceinline__ ushort_t f2bf(float f) {
  union { float f; unsigned u; } v; v.f = f;
  unsigned r = v.u + 0x7FFFu + ((v.u >> 16) & 1u);
  return (ushort_t)(r >> 16);
}
__device__ __forceinline__ float bf2f(ushort_t u) {
  union { unsigned u; float f; } v; v.u = ((unsigned)u) << 16; return v.f;
}
__device__ __forceinline__ us4 f2bf4(f4 v) {
  us4 b; b.x = f2bf(v.x); b.y = f2bf(v.y); b.z = f2bf(v.z); b.w = f2bf(v.w); return b;
}
__device__ __forceinline__ f4 bf2f4(us4 b) {
  f4 v; v.x = bf2f(b.x); v.y = bf2f(b.y); v.z = bf2f(b.z); v.w = bf2f(b.w); return v;
}
__device__ __forceinline__ float rcpf(float x) { return __builtin_amdgcn_rcpf(x); }
__device__ __forceinline__ float sigf(float x) { return rcpf(1.0f + __expf(-x)); }
__device__ __forceinline__ float tanhf_(float x) {
  return 1.0f - 2.0f * rcpf(1.0f + __expf(2.0f * x));
}
__device__ __forceinline__ f16v fzero() {
  f16v z;
  #pragma unroll
  for (int e = 0; e < 16; ++e) z[e] = 0.f;
  return z;
}

#define MFMA32(a, b, c) __builtin_amdgcn_mfma_f32_32x32x16_bf16((a), (b), (c), 0, 0, 0)

__global__ void prep_w(const float* __restrict__ cw1, const float* __restrict__ cw2,
                       const float* __restrict__ gw3, const float* __restrict__ gw4,
                       ushort_t* __restrict__ ws) {
  int tid = blockIdx.x * blockDim.x + threadIdx.x;
  int np = gridDim.x * blockDim.x;
  for (int i = tid; i < 384 * 320; i += np) ws[WS_W1 + i] = f2bf(cw1[i]);
  for (int i = tid; i < 384 * 128; i += np) ws[WS_W2 + i] = f2bf(cw2[i]);
  for (int i = tid; i < 640 * 32; i += np) {
    int n = i >> 5, k = i & 31;
    ws[WS_W3 + i] = (n < 600 && k < 20) ? f2bf(gw3[n * 20 + k]) : (ushort_t)0;
  }
  for (int i = tid; i < 640 * 224; i += np) {
    int n = i / 224, k = i - n * 224;
    ws[WS_W4 + i] = (n < 600 && k < 200) ? f2bf(gw4[n * 200 + k]) : (ushort_t)0;
  }
}

__global__ void prep_fac(const float* __restrict__ fw, ushort_t* __restrict__ ws) {
  int n = blockIdx.x;   // 64 rows
  int l = threadIdx.x;  // 64 lanes
  float ss = 0.f;
  for (int k = l; k < 200; k += 64) { float v = fw[n * 200 + k]; ss = fmaf(v, v, ss); }
  for (int off = 32; off; off >>= 1) ss += __shfl_down(ss, off, 64);
  ss = __shfl(ss, 0, 64);
  float inv = 1.0f / fmaxf(sqrtf(ss), 1e-12f);
  for (int k = l; k < 224; k += 64)
    ws[WS_W5 + n * 224 + k] = (k < 200) ? f2bf(fw[n * 200 + k] * inv) : (ushort_t)0;
}

__global__ __launch_bounds__(NT, 2) void decoder_kernel(
    const float* __restrict__ x, const float* __restrict__ h0, const float* __restrict__ eps,
    const float* __restrict__ gen_b_ih, const float* __restrict__ gen_b_hh,
    const float* __restrict__ con_b_ih, const float* __restrict__ con_b_hh,
    const float* __restrict__ co_w, const float* __restrict__ co_b,
    const ushort_t* __restrict__ ws, float* __restrict__ out)
{
  __shared__ __align__(16) unsigned char spool[POOLB];
  ushort_t* sA  = (ushort_t*)(spool + O_A);    // con_input [128][328]
  ushort_t* sGo = (ushort_t*)(spool + O_A);    // gen_state_old [128][216]
  ushort_t* sGn = (ushort_t*)(spool + O_GN);   // gen_state_new [128][216]
  ushort_t* sR2 = (ushort_t*)(spool + O_R2);   // con_state(128)+mean(4)+std(4)
  ushort_t* sR3 = (ushort_t*)(spool + O_R3);   // gen_input(20+12p)+factor(64)

  const int tid = threadIdx.x;
  const int rbase = blockIdx.x * RT;
  const int lane = tid & 63;
  const int w = tid >> 6;             // wave 0..7
  const int arow = lane & 31;         // 32x32 frag row/col within tile
  const int kh = (lane >> 5) << 3;    // k offset (0 or 8)
  const int qr4 = (lane >> 5) << 2;   // C/D row term: 4*(lane>>5)

  // ---------------- ph1: stage con_input, con_state, factor, ext
  #pragma unroll
  for (int it = 0; it < 16; ++it) {  // x[:,0:256] -> sA
    int idx = tid + it * NT;
    int r = idx >> 6, c4 = (idx & 63) << 2;
    f4 v = *(const f4*)&x[(size_t)(rbase + r) * XD + c4];
    *(us4*)&sA[r * STA + c4] = f2bf4(v);
  }
  {  // x[:,256:272] -> sR3 cols 4..20 (gen_input ext)
    int r = tid >> 2, e = (tid & 3) << 2;
    f4 v = *(const f4*)&x[(size_t)(rbase + r) * XD + 256 + e];
    *(us4*)&sR3[r * STR3 + 4 + e] = f2bf4(v);
  }
  #pragma unroll
  for (int it = 0; it < 8; ++it) {  // h0[:,200:328] -> sR2 (con_state_old)
    int idx = tid + it * NT;
    int r = idx >> 5, c4 = (idx & 31) << 2;
    f4 v = *(const f4*)&h0[(size_t)(rbase + r) * HD + 200 + c4];
    *(us4*)&sR2[r * STH + c4] = f2bf4(v);
  }
  #pragma unroll
  for (int it = 0; it < 4; ++it) {  // h0[:,356:420] -> sA cols 256..320
    int idx = tid + it * NT;
    int r = idx >> 4, c4 = (idx & 15) << 2;
    f4 v = *(const f4*)&h0[(size_t)(rbase + r) * HD + 356 + c4];
    *(us4*)&sA[r * STA + 256 + c4] = f2bf4(v);
  }
  if (tid < 384) {  // zero sR3 cols 20..32 (gi K-pad)
    int r = tid / 3, q = (tid - (tid / 3) * 3) << 2;
    us4 z = {0, 0, 0, 0};
    *(us4*)&sR3[r * STR3 + 20 + q] = z;
  }
  __syncthreads();  // B1

  const int cct = w & 3;          // con col-tile 0..3
  const int crh = w >> 2;         // con row half 0..1
  const int ccol = (cct << 5) + arow;  // 0..127
  const int crb = crh << 6;

  // ---------------- ph2: con GEMMs (2 row-tiles x 32-col tile per wave)
  f16v aR[2], aZ[2], aN[2], aHN[2];
  #pragma unroll
  for (int rt = 0; rt < 2; ++rt) {
    aR[rt] = fzero(); aZ[rt] = fzero(); aN[rt] = fzero(); aHN[rt] = fzero();
  }
  {
    const ushort_t* W2 = ws + WS_W2;
    #pragma unroll
    for (int k0 = 0; k0 < 128; k0 += 16) {  // gh (K=128)
      bf8 b0 = *(const bf8*)&W2[(size_t)(ccol) * 128 + k0 + kh];
      bf8 b1 = *(const bf8*)&W2[(size_t)(128 + ccol) * 128 + k0 + kh];
      bf8 bm = *(const bf8*)&W2[(size_t)(256 + ccol) * 128 + k0 + kh];
      #pragma unroll
      for (int rt = 0; rt < 2; ++rt) {
        bf8 a = *(const bf8*)&sR2[(crb + rt * 32 + arow) * STH + k0 + kh];
        aR[rt] = MFMA32(a, b0, aR[rt]);
        aZ[rt] = MFMA32(a, b1, aZ[rt]);
        aHN[rt] = MFMA32(a, bm, aHN[rt]);
      }
    }
    const ushort_t* W1 = ws + WS_W1;
    #pragma unroll
    for (int k0 = 0; k0 < 320; k0 += 16) {  // gi (K=320)
      bf8 b0 = *(const bf8*)&W1[(size_t)(ccol) * 320 + k0 + kh];
      bf8 b1 = *(const bf8*)&W1[(size_t)(128 + ccol) * 320 + k0 + kh];
      bf8 bm = *(const bf8*)&W1[(size_t)(256 + ccol) * 320 + k0 + kh];
      #pragma unroll
      for (int rt = 0; rt < 2; ++rt) {
        bf8 a = *(const bf8*)&sA[(crb + rt * 32 + arow) * STA + k0 + kh];
        aR[rt] = MFMA32(a, b0, aR[rt]);
        aZ[rt] = MFMA32(a, b1, aZ[rt]);
        aN[rt] = MFMA32(a, bm, aN[rt]);
      }
    }
  }
  __syncthreads();  // B2 (sA + sR2 frag reads done)

  // ---------------- ph3: stage gen_state_old (over dead sA) || elementwise
  for (int idx = tid; idx < 128 * 54; idx += NT) {
    int r = idx / 54, u = idx - (idx / 54) * 54;
    if (u < 50) {
      f4 v = *(const f4*)&h0[(size_t)(rbase + r) * HD + (u << 2)];
      *(us4*)&sGo[r * STG + (u << 2)] = f2bf4(v);
    } else {
      us4 z = {0, 0, 0, 0};
      *(us4*)&sGo[r * STG + 200 + ((u - 50) << 2)] = z;  // gh K-pad
    }
  }
  {
    float brr = con_b_ih[ccol] + con_b_hh[ccol];
    float brz = con_b_ih[128 + ccol] + con_b_hh[128 + ccol];
    float bin = con_b_ih[256 + ccol], bhn = con_b_hh[256 + ccol];
    #pragma unroll
    for (int rt = 0; rt < 2; ++rt) {
      #pragma unroll
      for (int g = 0; g < 16; ++g) {
        int row = crb + rt * 32 + (g & 3) + ((g >> 2) << 3) + qr4;
        float hold = bf2f(sR2[row * STH + ccol]);
        float rr = sigf(aR[rt][g] + brr);
        float zz = sigf(aZ[rt][g] + brz);
        float nn = tanhf_(aN[rt][g] + bin + rr * (aHN[rt][g] + bhn));
        float hv = (1.f - zz) * nn + zz * hold;
        hv = fminf(fmaxf(hv, -5.f), 5.f);
        sR2[row * STH + ccol] = f2bf(hv);  // own (row,col) only: no race
      }
    }
  }
  __syncthreads();  // B3

  // ---------------- ph4: co linear + reparam (f32 VALU; 128 rows x 8 cols)
  {
    int cn = tid & 7;
    #pragma unroll
    for (int half = 0; half < 2; ++half) {
      int crow = (tid >> 3) + half * 64;
      float acc = co_b[cn];
      #pragma unroll 8
      for (int k0 = 0; k0 < 128; k0 += 4) {
        f4 hv = bf2f4(*(const us4*)&sR2[crow * STH + k0]);
        f4 wv = *(const f4*)&co_w[cn * 128 + k0];
        acc = fmaf(hv.x, wv.x, acc);
        acc = fmaf(hv.y, wv.y, acc);
        acc = fmaf(hv.z, wv.z, acc);
        acc = fmaf(hv.w, wv.w, acc);
      }
      float lv = __shfl(acc, lane + 4, 64);  // partner lane holds logvar
      if (cn < 4) {
        float stdv = __expf(0.5f * lv);
        float ov = fmaf(stdv, eps[(size_t)(rbase + crow) * 4 + cn], acc);
        sR2[crow * STH + 128 + cn] = f2bf(acc);
        sR2[crow * STH + 132 + cn] = f2bf(stdv);
        sR3[crow * STR3 + cn] = f2bf(ov);
      }
    }
  }
  __syncthreads();  // B4

  // ---------------- ph5: flush out[:,200:336) from sR2 (coalesced span)
  for (int idx = tid; idx < 128 * 34; idx += NT) {
    int r = idx / 34, c4 = (idx - (idx / 34) * 34) << 2;
    f4 v = bf2f4(*(const us4*)&sR2[r * STH + c4]);
    *(f4*)&out[(size_t)(rbase + r) * HD + 200 + c4] = v;
  }
  __syncthreads();  // B5 (sR2 dead; sGn region live from here)

  // ---------------- ph6: gen GRU (14 jobs over 8 waves)
  {  // zero sGn K-pad cols 200..216
    int r = tid >> 2, q = (tid & 3) << 2;
    us4 z = {0, 0, 0, 0};
    *(us4*)&sGn[r * STG + 200 + q] = z;
  }
  {
    const ushort_t* W3 = ws + WS_W3;
    const ushort_t* W4 = ws + WS_W4;
    for (int j = w; j < 14; j += 8) {
      int gct = j >> 1;          // col-tile 0..6
      int grb = (j & 1) << 6;    // row half base
      int c = (gct << 5) + arow; // output column 0..223 (valid < 200)
      f16v gR[2], gZ[2], gN[2], gHN[2];
      #pragma unroll
      for (int rt = 0; rt < 2; ++rt) {
        gR[rt] = fzero(); gZ[rt] = fzero(); gN[rt] = fzero(); gHN[rt] = fzero();
      }
      #pragma unroll
      for (int k0 = 0; k0 < 32; k0 += 16) {  // gi (K=32 padded)
        bf8 b0 = *(const bf8*)&W3[(size_t)(c) * 32 + k0 + kh];
        bf8 b1 = *(const bf8*)&W3[(size_t)(200 + c) * 32 + k0 + kh];
        bf8 bm = *(const bf8*)&W3[(size_t)(400 + c) * 32 + k0 + kh];
        #pragma unroll
        for (int rt = 0; rt < 2; ++rt) {
          bf8 a = *(const bf8*)&sR3[(grb + rt * 32 + arow) * STR3 + k0 + kh];
          gR[rt] = MFMA32(a, b0, gR[rt]);
          gZ[rt] = MFMA32(a, b1, gZ[rt]);
          gN[rt] = MFMA32(a, bm, gN[rt]);
        }
      }
      #pragma unroll
      for (int k0 = 0; k0 < 224; k0 += 16) {  // gh (K=200 padded)
        bf8 b0 = *(const bf8*)&W4[(size_t)(c) * 224 + k0 + kh];
        bf8 b1 = *(const bf8*)&W4[(size_t)(200 + c) * 224 + k0 + kh];
        bf8 bm = *(const bf8*)&W4[(size_t)(400 + c) * 224 + k0 + kh];
        #pragma unroll
        for (int rt = 0; rt < 2; ++rt) {
          bf8 a = *(const bf8*)&sGo[(grb + rt * 32 + arow) * STG + k0 + kh];
          gR[rt] = MFMA32(a, b0, gR[rt]);
          gZ[rt] = MFMA32(a, b1, gZ[rt]);
          gHN[rt] = MFMA32(a, bm, gHN[rt]);
        }
      }
      if (c < 200) {
        float brr = gen_b_ih[c] + gen_b_hh[c];
        float brz = gen_b_ih[200 + c] + gen_b_hh[200 + c];
        float bin = gen_b_ih[400 + c], bhn = gen_b_hh[400 + c];
        #pragma unroll
        for (int rt = 0; rt < 2; ++rt) {
          #pragma unroll
          for (int g = 0; g < 16; ++g) {
            int row = grb + rt * 32 + (g & 3) + ((g >> 2) << 3) + qr4;
            float hold = bf2f(sGo[row * STG + c]);
            float rr = sigf(gR[rt][g] + brr);
            float zz = sigf(gZ[rt][g] + brz);
            float nn = tanhf_(gN[rt][g] + bin + rr * (gHN[rt][g] + bhn));
            float hv = (1.f - zz) * nn + zz * hold;
            hv = fminf(fmaxf(hv, -5.f), 5.f);
            sGn[row * STG + c] = f2bf(hv);
          }
        }
      }
    }
  }
  __syncthreads();  // B6

  // ---------------- ph7: factor = gen_state_new @ normed_fac^T -> sR3[20:84)
  {
    const ushort_t* W5 = ws + WS_W5;
    int fct = w & 1;          // col-tile 0..1
    int frt = w >> 1;         // row-tile 0..3
    int fc = (fct << 5) + arow;  // 0..63
    f16v fa = fzero();
    #pragma unroll
    for (int k0 = 0; k0 < 224; k0 += 16) {
      bf8 b = *(const bf8*)&W5[(size_t)(fc) * 224 + k0 + kh];
      bf8 a = *(const bf8*)&sGn[(frt * 32 + arow) * STG + k0 + kh];
      fa = MFMA32(a, b, fa);
    }
    #pragma unroll
    for (int g = 0; g < 16; ++g) {
      int row = frt * 32 + (g & 3) + ((g >> 2) << 3) + qr4;
      sR3[row * STR3 + 20 + fc] = f2bf(fa[g]);
    }
  }
  __syncthreads();  // B7

  // ---------------- ph8: final flush out[:,0:200) + out[:,336:420)
  for (int idx = tid; idx < 128 * 71; idx += NT) {
    int r = idx / 71, u = idx - (idx / 71) * 71;
    if (u < 50) {
      f4 v = bf2f4(*(const us4*)&sGn[r * STG + (u << 2)]);
      *(f4*)&out[(size_t)(rbase + r) * HD + (u << 2)] = v;
    } else {
      int u2 = u - 50;
      f4 v = bf2f4(*(const us4*)&sR3[r * STR3 + (u2 << 2)]);
      *(f4*)&out[(size_t)(rbase + r) * HD + 336 + (u2 << 2)] = v;
    }
  }
}

extern "C" void kernel_launch(void* const* d_in, const int* in_sizes, int n_in,
                              void* d_out, int out_size, void* d_ws, size_t ws_size,
                              hipStream_t stream) {
  const float* x        = (const float*)d_in[0];
  const float* h0       = (const float*)d_in[1];
  const float* eps      = (const float*)d_in[2];
  const float* gen_w_ih = (const float*)d_in[3];
  const float* gen_w_hh = (const float*)d_in[4];
  const float* gen_b_ih = (const float*)d_in[5];
  const float* gen_b_hh = (const float*)d_in[6];
  const float* con_w_ih = (const float*)d_in[7];
  const float* con_w_hh = (const float*)d_in[8];
  const float* con_b_ih = (const float*)d_in[9];
  const float* con_b_hh = (const float*)d_in[10];
  const float* co_w     = (const float*)d_in[11];
  const float* co_b     = (const float*)d_in[12];
  const float* fac_w    = (const float*)d_in[13];
  float* out = (float*)d_out;
  ushort_t* ws = (ushort_t*)d_ws;

  hipLaunchKernelGGL(prep_w, dim3(256), dim3(512), 0, stream,
                     con_w_ih, con_w_hh, gen_w_ih, gen_w_hh, ws);
  hipLaunchKernelGGL(prep_fac, dim3(64), dim3(64), 0, stream, fac_w, ws);

  int nrows = in_sizes[2] / 4;  // eps is (B,4)
  int grid = nrows / RT;        // 512
  hipLaunchKernelGGL(decoder_kernel, dim3(grid), dim3(NT), 0, stream,
                     x, h0, eps, gen_b_ih, gen_b_hh, con_b_ih, con_b_hh,
                     co_w, co_b, ws, out);
}

// Round 12
// 160.867 us; speedup vs baseline: 1.1102x; 1.1102x over previous
//
#include <hip/hip_runtime.h>
#include <hip/hip_bf16.h>
#include <math.h>

// DecoderCell fused kernel — Round 12: exact R9 structure (RT=128/NT=512,
// rcp activations, 16x16x32 MFMA). Single change: all f32<->bf16 conversions
// via compiler-native casts (__float22bfloat162_rn -> v_cvt_pk_bf16_f32,
// 1 op per 2 elements) instead of the 4-op bit-trick. Per m240: native cast
// is the fast path; R8's failure was hand-written asm (register aliasing),
// not the instruction.

#define NT 512
#define RT 128
#define XD 272
#define HD 420

typedef unsigned short ushort_t;
typedef __attribute__((ext_vector_type(8))) short bf8;
typedef __attribute__((ext_vector_type(4))) float f4;
typedef __attribute__((ext_vector_type(4))) unsigned short us4;

// ws layout (bf16 element offsets)
#define WS_W1 0         // con_w_ih [384][320]
#define WS_W2 122880    // con_w_hh [384][128]
#define WS_W3 172032    // gen_w_ih [608][32]  (K 20->32 pad, rows 600-607 zero)
#define WS_W4 191488    // gen_w_hh [608][224] (K 200->224 pad, rows 600-607 zero)
#define WS_W5 327680    // normed fac_w [64][224] (K pad zero)

#define STA 328
#define STG 216
#define STH 136
#define STR3 88

#define O_A   0        // sA [128][328] = 83,968 ; later sGo [128][216]=55,296
#define O_GN  55296    // sGn [128][216] = 55,296
#define O_R2  83968    // sR2 [128][136] = 34,816
#define O_R3  118784   // sR3 [128][88]  = 22,528
#define POOLB 141312

__device__ __forceinline__ ushort_t f2bf(float f) {
  __hip_bfloat16 h = __float2bfloat16(f);
  return *reinterpret_cast<ushort_t*>(&h);
}
__device__ __forceinline__ float bf2f(ushort_t u) {
  union { unsigned u; float f; } v; v.u = ((unsigned)u) << 16; return v.f;
}
__device__ __forceinline__ us4 f2bf4(f4 v) {
  __hip_bfloat162 lo = __float22bfloat162_rn(float2{v.x, v.y});
  __hip_bfloat162 hi = __float22bfloat162_rn(float2{v.z, v.w});
  us4 b;
  b.x = *reinterpret_cast<ushort_t*>(&lo.x);
  b.y = *reinterpret_cast<ushort_t*>(&lo.y);
  b.z = *reinterpret_cast<ushort_t*>(&hi.x);
  b.w = *reinterpret_cast<ushort_t*>(&hi.y);
  return b;
}
__device__ __forceinline__ f4 bf2f4(us4 b) {
  f4 v; v.x = bf2f(b.x); v.y = bf2f(b.y); v.z = bf2f(b.z); v.w = bf2f(b.w); return v;
}
__device__ __forceinline__ float rcpf(float x) { return __builtin_amdgcn_rcpf(x); }
__device__ __forceinline__ float sigf(float x) { return rcpf(1.0f + __expf(-x)); }
__device__ __forceinline__ float tanhf_(float x) {
  return 1.0f - 2.0f * rcpf(1.0f + __expf(2.0f * x));
}

#define MFMA(a, b, c) __builtin_amdgcn_mfma_f32_16x16x32_bf16((a), (b), (c), 0, 0, 0)

__global__ void prep_w(const float* __restrict__ cw1, const float* __restrict__ cw2,
                       const float* __restrict__ gw3, const float* __restrict__ gw4,
                       ushort_t* __restrict__ ws) {
  int tid = blockIdx.x * blockDim.x + threadIdx.x;
  int np = gridDim.x * blockDim.x;
  for (int i = tid; i < 384 * 320; i += np) ws[WS_W1 + i] = f2bf(cw1[i]);
  for (int i = tid; i < 384 * 128; i += np) ws[WS_W2 + i] = f2bf(cw2[i]);
  for (int i = tid; i < 608 * 32; i += np) {
    int n = i >> 5, k = i & 31;
    ws[WS_W3 + i] = (n < 600 && k < 20) ? f2bf(gw3[n * 20 + k]) : (ushort_t)0;
  }
  for (int i = tid; i < 608 * 224; i += np) {
    int n = i / 224, k = i - n * 224;
    ws[WS_W4 + i] = (n < 600 && k < 200) ? f2bf(gw4[n * 200 + k]) : (ushort_t)0;
  }
}

__global__ void prep_fac(const float* __restrict__ fw, ushort_t* __restrict__ ws) {
  int n = blockIdx.x;   // 64 rows
  int l = threadIdx.x;  // 64 lanes
  float ss = 0.f;
  for (int k = l; k < 200; k += 64) { float v = fw[n * 200 + k]; ss = fmaf(v, v, ss); }
  for (int off = 32; off; off >>= 1) ss += __shfl_down(ss, off, 64);
  ss = __shfl(ss, 0, 64);
  float inv = 1.0f / fmaxf(sqrtf(ss), 1e-12f);
  for (int k = l; k < 224; k += 64)
    ws[WS_W5 + n * 224 + k] = (k < 200) ? f2bf(fw[n * 200 + k] * inv) : (ushort_t)0;
}

__global__ __launch_bounds__(NT, 2) void decoder_kernel(
    const float* __restrict__ x, const float* __restrict__ h0, const float* __restrict__ eps,
    const float* __restrict__ gen_b_ih, const float* __restrict__ gen_b_hh,
    const float* __restrict__ con_b_ih, const float* __restrict__ con_b_hh,
    const float* __restrict__ co_w, const float* __restrict__ co_b,
    const ushort_t* __restrict__ ws, float* __restrict__ out)
{
  __shared__ __align__(16) unsigned char spool[POOLB];
  ushort_t* sA  = (ushort_t*)(spool + O_A);    // con_input [128][328]
  ushort_t* sGo = (ushort_t*)(spool + O_A);    // gen_state_old [128][216]
  ushort_t* sGn = (ushort_t*)(spool + O_GN);   // gen_state_new [128][216]
  ushort_t* sR2 = (ushort_t*)(spool + O_R2);   // con_state(128)+mean(4)+std(4)
  ushort_t* sR3 = (ushort_t*)(spool + O_R3);   // gen_input(20+12p)+factor(64)

  const int tid = threadIdx.x;
  const int rbase = blockIdx.x * RT;
  const int lane = tid & 63;
  const int w = tid >> 6;
  const int bn = lane & 15;           // frag row/col within 16
  const int kq = (lane >> 4) << 3;    // k offset of quarter-wave
  const int qrow = (lane >> 4) << 2;  // C/D row offset of quarter-wave

  // ---------------- ph1: stage con_input, con_state, factor, ext
  #pragma unroll
  for (int it = 0; it < 16; ++it) {  // x[:,0:256] -> sA
    int idx = tid + it * NT;
    int r = idx >> 6, c4 = (idx & 63) << 2;
    f4 v = *(const f4*)&x[(size_t)(rbase + r) * XD + c4];
    *(us4*)&sA[r * STA + c4] = f2bf4(v);
  }
  {  // x[:,256:272] -> sR3 cols 4..20 (gen_input ext)
    int r = tid >> 2, e = (tid & 3) << 2;
    f4 v = *(const f4*)&x[(size_t)(rbase + r) * XD + 256 + e];
    *(us4*)&sR3[r * STR3 + 4 + e] = f2bf4(v);
  }
  #pragma unroll
  for (int it = 0; it < 8; ++it) {  // h0[:,200:328] -> sR2 (con_state_old)
    int idx = tid + it * NT;
    int r = idx >> 5, c4 = (idx & 31) << 2;
    f4 v = *(const f4*)&h0[(size_t)(rbase + r) * HD + 200 + c4];
    *(us4*)&sR2[r * STH + c4] = f2bf4(v);
  }
  #pragma unroll
  for (int it = 0; it < 4; ++it) {  // h0[:,356:420] -> sA cols 256..320
    int idx = tid + it * NT;
    int r = idx >> 4, c4 = (idx & 15) << 2;
    f4 v = *(const f4*)&h0[(size_t)(rbase + r) * HD + 356 + c4];
    *(us4*)&sA[r * STA + 256 + c4] = f2bf4(v);
  }
  if (tid < 384) {  // zero sR3 cols 20..32 (gi K-pad)
    int r = tid / 3, q = (tid - (tid / 3) * 3) << 2;
    us4 z = {0, 0, 0, 0};
    *(us4*)&sR3[r * STR3 + 20 + q] = z;
  }
  __syncthreads();  // B1

  const int col = (w << 4) + bn;  // wave's con output column (0..127)

  // ---------------- ph2: con GEMMs (8 row-tiles/wave), batched prefetch
  f4 aR[8], aZ[8], aN[8], aHN[8];
  #pragma unroll
  for (int ri = 0; ri < 8; ++ri) {
    aR[ri] = (f4){0.f, 0.f, 0.f, 0.f};
    aZ[ri] = (f4){0.f, 0.f, 0.f, 0.f};
    aN[ri] = (f4){0.f, 0.f, 0.f, 0.f};
    aHN[ri] = (f4){0.f, 0.f, 0.f, 0.f};
  }
  {
    const ushort_t* W2 = ws + WS_W2;
    const ushort_t* W1 = ws + WS_W1;
    bf8 w2f[4][3], w1a[5][3];
    #pragma unroll
    for (int k = 0; k < 4; ++k) {
      w2f[k][0] = *(const bf8*)&W2[(size_t)(col) * 128 + k * 32 + kq];
      w2f[k][1] = *(const bf8*)&W2[(size_t)(128 + col) * 128 + k * 32 + kq];
      w2f[k][2] = *(const bf8*)&W2[(size_t)(256 + col) * 128 + k * 32 + kq];
    }
    #pragma unroll
    for (int k = 0; k < 5; ++k) {
      w1a[k][0] = *(const bf8*)&W1[(size_t)(col) * 320 + k * 32 + kq];
      w1a[k][1] = *(const bf8*)&W1[(size_t)(128 + col) * 320 + k * 32 + kq];
      w1a[k][2] = *(const bf8*)&W1[(size_t)(256 + col) * 320 + k * 32 + kq];
    }
    #pragma unroll
    for (int k = 0; k < 4; ++k) {  // gh (K=128)
      #pragma unroll
      for (int ri = 0; ri < 8; ++ri) {
        bf8 a = *(const bf8*)&sR2[(ri * 16 + bn) * STH + k * 32 + kq];
        aR[ri] = MFMA(a, w2f[k][0], aR[ri]);
        aZ[ri] = MFMA(a, w2f[k][1], aZ[ri]);
        aHN[ri] = MFMA(a, w2f[k][2], aHN[ri]);
      }
    }
    bf8 w1b[5][3];
    #pragma unroll
    for (int k = 0; k < 5; ++k) {
      w1b[k][0] = *(const bf8*)&W1[(size_t)(col) * 320 + (k + 5) * 32 + kq];
      w1b[k][1] = *(const bf8*)&W1[(size_t)(128 + col) * 320 + (k + 5) * 32 + kq];
      w1b[k][2] = *(const bf8*)&W1[(size_t)(256 + col) * 320 + (k + 5) * 32 + kq];
    }
    #pragma unroll
    for (int k = 0; k < 5; ++k) {  // gi batch A
      #pragma unroll
      for (int ri = 0; ri < 8; ++ri) {
        bf8 a = *(const bf8*)&sA[(ri * 16 + bn) * STA + k * 32 + kq];
        aR[ri] = MFMA(a, w1a[k][0], aR[ri]);
        aZ[ri] = MFMA(a, w1a[k][1], aZ[ri]);
        aN[ri] = MFMA(a, w1a[k][2], aN[ri]);
      }
    }
    #pragma unroll
    for (int k = 0; k < 5; ++k) {  // gi batch B
      #pragma unroll
      for (int ri = 0; ri < 8; ++ri) {
        bf8 a = *(const bf8*)&sA[(ri * 16 + bn) * STA + (k + 5) * 32 + kq];
        aR[ri] = MFMA(a, w1b[k][0], aR[ri]);
        aZ[ri] = MFMA(a, w1b[k][1], aZ[ri]);
        aN[ri] = MFMA(a, w1b[k][2], aN[ri]);
      }
    }
  }
  __syncthreads();  // B2 (sA + sR2 frag reads done)

  // ---------------- ph3: stage gen_state_old (over dead sA) || elementwise
  for (int idx = tid; idx < 128 * 54; idx += NT) {
    int r = idx / 54, u = idx - (idx / 54) * 54;
    if (u < 50) {
      f4 v = *(const f4*)&h0[(size_t)(rbase + r) * HD + (u << 2)];
      *(us4*)&sGo[r * STG + (u << 2)] = f2bf4(v);
    } else {
      us4 z = {0, 0, 0, 0};
      *(us4*)&sGo[r * STG + 200 + ((u - 50) << 2)] = z;  // gh K-pad
    }
  }
  {
    float brr = con_b_ih[col] + con_b_hh[col];
    float brz = con_b_ih[128 + col] + con_b_hh[128 + col];
    float bin = con_b_ih[256 + col], bhn = con_b_hh[256 + col];
    #pragma unroll
    for (int ri = 0; ri < 8; ++ri) {
      #pragma unroll
      for (int j = 0; j < 4; ++j) {
        int row = ri * 16 + qrow + j;
        float hold = bf2f(sR2[row * STH + col]);
        float rr = sigf(aR[ri][j] + brr);
        float zz = sigf(aZ[ri][j] + brz);
        float nn = tanhf_(aN[ri][j] + bin + rr * (aHN[ri][j] + bhn));
        float hv = (1.f - zz) * nn + zz * hold;
        hv = fminf(fmaxf(hv, -5.f), 5.f);
        sR2[row * STH + col] = f2bf(hv);  // own (row,col) only: no race
      }
    }
  }
  __syncthreads();  // B3

  // ---------------- ph4: co linear + reparam (f32 VALU; 128 rows x 8 cols)
  {
    int cn = tid & 7;
    #pragma unroll
    for (int half = 0; half < 2; ++half) {
      int crow = (tid >> 3) + half * 64;
      float acc = co_b[cn];
      #pragma unroll 8
      for (int k0 = 0; k0 < 128; k0 += 4) {
        f4 hv = bf2f4(*(const us4*)&sR2[crow * STH + k0]);
        f4 wv = *(const f4*)&co_w[cn * 128 + k0];
        acc = fmaf(hv.x, wv.x, acc);
        acc = fmaf(hv.y, wv.y, acc);
        acc = fmaf(hv.z, wv.z, acc);
        acc = fmaf(hv.w, wv.w, acc);
      }
      float lv = __shfl(acc, lane + 4, 64);  // partner lane holds logvar
      if (cn < 4) {
        float stdv = __expf(0.5f * lv);
        float ov = fmaf(stdv, eps[(size_t)(rbase + crow) * 4 + cn], acc);
        sR2[crow * STH + 128 + cn] = f2bf(acc);
        sR2[crow * STH + 132 + cn] = f2bf(stdv);
        sR3[crow * STR3 + cn] = f2bf(ov);
      }
    }
  }
  __syncthreads();  // B4

  // ---------------- ph5: flush out[:,200:336) from sR2 (coalesced span)
  for (int idx = tid; idx < 128 * 34; idx += NT) {
    int r = idx / 34, c4 = (idx - (idx / 34) * 34) << 2;
    f4 v = bf2f4(*(const us4*)&sR2[r * STH + c4]);
    *(f4*)&out[(size_t)(rbase + r) * HD + 200 + c4] = v;
  }
  __syncthreads();  // B5 (sR2 dead; sGn region live from here)

  // ---------------- ph6: gen GRU (13 col-tiles over 8 waves)
  {  // zero sGn K-pad cols 200..216
    int r = tid >> 2, q = (tid & 3) << 2;
    us4 z = {0, 0, 0, 0};
    *(us4*)&sGn[r * STG + 200 + q] = z;
  }
  {
    const ushort_t* W3 = ws + WS_W3;
    const ushort_t* W4 = ws + WS_W4;
    for (int t = w; t < 13; t += 8) {
      int c = (t << 4) + bn;  // output column (valid < 200)
      bf8 w3f[3], w4a[4][3];
      w3f[0] = *(const bf8*)&W3[(size_t)(c) * 32 + kq];
      w3f[1] = *(const bf8*)&W3[(size_t)(200 + c) * 32 + kq];
      w3f[2] = *(const bf8*)&W3[(size_t)(400 + c) * 32 + kq];
      #pragma unroll
      for (int k = 0; k < 4; ++k) {
        w4a[k][0] = *(const bf8*)&W4[(size_t)(c) * 224 + k * 32 + kq];
        w4a[k][1] = *(const bf8*)&W4[(size_t)(200 + c) * 224 + k * 32 + kq];
        w4a[k][2] = *(const bf8*)&W4[(size_t)(400 + c) * 224 + k * 32 + kq];
      }
      f4 gR[8], gZ[8], gN[8], gHN[8];
      #pragma unroll
      for (int ri = 0; ri < 8; ++ri) {
        gR[ri] = (f4){0.f, 0.f, 0.f, 0.f};
        gZ[ri] = (f4){0.f, 0.f, 0.f, 0.f};
        gN[ri] = (f4){0.f, 0.f, 0.f, 0.f};
        gHN[ri] = (f4){0.f, 0.f, 0.f, 0.f};
      }
      #pragma unroll
      for (int ri = 0; ri < 8; ++ri) {  // gi (K=32)
        bf8 a = *(const bf8*)&sR3[(ri * 16 + bn) * STR3 + kq];
        gR[ri] = MFMA(a, w3f[0], gR[ri]);
        gZ[ri] = MFMA(a, w3f[1], gZ[ri]);
        gN[ri] = MFMA(a, w3f[2], gN[ri]);
      }
      bf8 w4b[3][3];
      #pragma unroll
      for (int k = 0; k < 3; ++k) {
        w4b[k][0] = *(const bf8*)&W4[(size_t)(c) * 224 + (k + 4) * 32 + kq];
        w4b[k][1] = *(const bf8*)&W4[(size_t)(200 + c) * 224 + (k + 4) * 32 + kq];
        w4b[k][2] = *(const bf8*)&W4[(size_t)(400 + c) * 224 + (k + 4) * 32 + kq];
      }
      #pragma unroll
      for (int k = 0; k < 4; ++k) {  // gh batch A
        #pragma unroll
        for (int ri = 0; ri < 8; ++ri) {
          bf8 a = *(const bf8*)&sGo[(ri * 16 + bn) * STG + k * 32 + kq];
          gR[ri] = MFMA(a, w4a[k][0], gR[ri]);
          gZ[ri] = MFMA(a, w4a[k][1], gZ[ri]);
          gHN[ri] = MFMA(a, w4a[k][2], gHN[ri]);
        }
      }
      #pragma unroll
      for (int k = 0; k < 3; ++k) {  // gh batch B
        #pragma unroll
        for (int ri = 0; ri < 8; ++ri) {
          bf8 a = *(const bf8*)&sGo[(ri * 16 + bn) * STG + (k + 4) * 32 + kq];
          gR[ri] = MFMA(a, w4b[k][0], gR[ri]);
          gZ[ri] = MFMA(a, w4b[k][1], gZ[ri]);
          gHN[ri] = MFMA(a, w4b[k][2], gHN[ri]);
        }
      }
      if (c < 200) {
        float brr = gen_b_ih[c] + gen_b_hh[c];
        float brz = gen_b_ih[200 + c] + gen_b_hh[200 + c];
        float bin = gen_b_ih[400 + c], bhn = gen_b_hh[400 + c];
        #pragma unroll
        for (int ri = 0; ri < 8; ++ri) {
          #pragma unroll
          for (int j = 0; j < 4; ++j) {
            int row = ri * 16 + qrow + j;
            float hold = bf2f(sGo[row * STG + c]);
            float rr = sigf(gR[ri][j] + brr);
            float zz = sigf(gZ[ri][j] + brz);
            float nn = tanhf_(gN[ri][j] + bin + rr * (gHN[ri][j] + bhn));
            float hv = (1.f - zz) * nn + zz * hold;
            hv = fminf(fmaxf(hv, -5.f), 5.f);
            sGn[row * STG + c] = f2bf(hv);
          }
        }
      }
    }
  }
  __syncthreads();  // B6

  // ---------------- ph7: factor = gen_state_new @ normed_fac^T -> sR3[20:84)
  {
    const ushort_t* W5 = ws + WS_W5;
    #pragma unroll
    for (int job = 0; job < 4; ++job) {
      int ri = ((w & 3) << 1) + (job & 1);      // 0..7
      int ct = ((w >> 2) << 1) + (job >> 1);    // 0..3
      bf8 w5f[7];
      #pragma unroll
      for (int k = 0; k < 7; ++k)
        w5f[k] = *(const bf8*)&W5[(size_t)((ct << 4) + bn) * 224 + k * 32 + kq];
      f4 acc = (f4){0.f, 0.f, 0.f, 0.f};
      #pragma unroll
      for (int k = 0; k < 7; ++k) {
        bf8 a = *(const bf8*)&sGn[(ri * 16 + bn) * STG + k * 32 + kq];
        acc = MFMA(a, w5f[k], acc);
      }
      #pragma unroll
      for (int j = 0; j < 4; ++j) {
        int row = ri * 16 + qrow + j;
        sR3[row * STR3 + 20 + (ct << 4) + bn] = f2bf(acc[j]);
      }
    }
  }
  __syncthreads();  // B7

  // ---------------- ph8: final flush out[:,0:200) + out[:,336:420)
  for (int idx = tid; idx < 128 * 71; idx += NT) {
    int r = idx / 71, u = idx - (idx / 71) * 71;
    if (u < 50) {
      f4 v = bf2f4(*(const us4*)&sGn[r * STG + (u << 2)]);
      *(f4*)&out[(size_t)(rbase + r) * HD + (u << 2)] = v;
    } else {
      int u2 = u - 50;
      f4 v = bf2f4(*(const us4*)&sR3[r * STR3 + (u2 << 2)]);
      *(f4*)&out[(size_t)(rbase + r) * HD + 336 + (u2 << 2)] = v;
    }
  }
}

extern "C" void kernel_launch(void* const* d_in, const int* in_sizes, int n_in,
                              void* d_out, int out_size, void* d_ws, size_t ws_size,
                              hipStream_t stream) {
  const float* x        = (const float*)d_in[0];
  const float* h0       = (const float*)d_in[1];
  const float* eps      = (const float*)d_in[2];
  const float* gen_w_ih = (const float*)d_in[3];
  const float* gen_w_hh = (const float*)d_in[4];
  const float* gen_b_ih = (const float*)d_in[5];
  const float* gen_b_hh = (const float*)d_in[6];
  const float* con_w_ih = (const float*)d_in[7];
  const float* con_w_hh = (const float*)d_in[8];
  const float* con_b_ih = (const float*)d_in[9];
  const float* con_b_hh = (const float*)d_in[10];
  const float* co_w     = (const float*)d_in[11];
  const float* co_b     = (const float*)d_in[12];
  const float* fac_w    = (const float*)d_in[13];
  float* out = (float*)d_out;
  ushort_t* ws = (ushort_t*)d_ws;

  hipLaunchKernelGGL(prep_w, dim3(256), dim3(512), 0, stream,
                     con_w_ih, con_w_hh, gen_w_ih, gen_w_hh, ws);
  hipLaunchKernelGGL(prep_fac, dim3(64), dim3(64), 0, stream, fac_w, ws);

  int nrows = in_sizes[2] / 4;  // eps is (B,4)
  int grid = nrows / RT;        // 512
  hipLaunchKernelGGL(decoder_kernel, dim3(grid), dim3(NT), 0, stream,
                     x, h0, eps, gen_b_ih, gen_b_hh, con_b_ih, con_b_hh,
                     co_w, co_b, ws, out);
}

// Round 13
// 153.142 us; speedup vs baseline: 1.1662x; 1.0504x over previous
//
#include <hip/hip_runtime.h>
#include <math.h>

// DecoderCell fused kernel — Round 13: R9 base (RT=128/NT=512, rcp diet,
// bit-trick conversions) with flush phases ELIMINATED: all outputs stored
// directly to out (f32) in the compute epilogues. Each wave's stores are
// 16-consecutive-col x 4-row = 64B chunks; 8 waves cover adjacent chunks ->
// L2 write-combines. Removes ph5+ph8 (~17us of serial flush) and 3 barriers.
// LDS keeps only MFMA-consumed data: sR2 (con_state), sR3 (gen_input), sGn.

#define NT 512
#define RT 128
#define XD 272
#define HD 420

typedef unsigned short ushort_t;
typedef __attribute__((ext_vector_type(8))) short bf8;
typedef __attribute__((ext_vector_type(4))) float f4;
typedef __attribute__((ext_vector_type(4))) unsigned short us4;

// ws layout (bf16 element offsets)
#define WS_W1 0         // con_w_ih [384][320]
#define WS_W2 122880    // con_w_hh [384][128]
#define WS_W3 172032    // gen_w_ih [608][32]  (K 20->32 pad, rows 600-607 zero)
#define WS_W4 191488    // gen_w_hh [608][224] (K 200->224 pad, rows 600-607 zero)
#define WS_W5 327680    // normed fac_w [64][224] (K pad zero)

#define STA 328
#define STG 216
#define STH 136
#define STR3 88

#define O_A   0        // sA [128][328] = 83,968 ; later sGo [128][216]=55,296
#define O_GN  55296    // sGn [128][216] = 55,296
#define O_R2  83968    // sR2 [128][136] = 34,816
#define O_R3  118784   // sR3 [128][88]  = 22,528
#define POOLB 141312

__device__ __forceinline__ ushort_t f2bf(float f) {
  union { float f; unsigned u; } v; v.f = f;
  unsigned r = v.u + 0x7FFFu + ((v.u >> 16) & 1u);
  return (ushort_t)(r >> 16);
}
__device__ __forceinline__ float bf2f(ushort_t u) {
  union { unsigned u; float f; } v; v.u = ((unsigned)u) << 16; return v.f;
}
__device__ __forceinline__ us4 f2bf4(f4 v) {
  us4 b; b.x = f2bf(v.x); b.y = f2bf(v.y); b.z = f2bf(v.z); b.w = f2bf(v.w); return b;
}
__device__ __forceinline__ f4 bf2f4(us4 b) {
  f4 v; v.x = bf2f(b.x); v.y = bf2f(b.y); v.z = bf2f(b.z); v.w = bf2f(b.w); return v;
}
__device__ __forceinline__ float rcpf(float x) { return __builtin_amdgcn_rcpf(x); }
__device__ __forceinline__ float sigf(float x) { return rcpf(1.0f + __expf(-x)); }
__device__ __forceinline__ float tanhf_(float x) {
  return 1.0f - 2.0f * rcpf(1.0f + __expf(2.0f * x));
}

#define MFMA(a, b, c) __builtin_amdgcn_mfma_f32_16x16x32_bf16((a), (b), (c), 0, 0, 0)

__global__ void prep_w(const float* __restrict__ cw1, const float* __restrict__ cw2,
                       const float* __restrict__ gw3, const float* __restrict__ gw4,
                       ushort_t* __restrict__ ws) {
  int tid = blockIdx.x * blockDim.x + threadIdx.x;
  int np = gridDim.x * blockDim.x;
  for (int i = tid; i < 384 * 320; i += np) ws[WS_W1 + i] = f2bf(cw1[i]);
  for (int i = tid; i < 384 * 128; i += np) ws[WS_W2 + i] = f2bf(cw2[i]);
  for (int i = tid; i < 608 * 32; i += np) {
    int n = i >> 5, k = i & 31;
    ws[WS_W3 + i] = (n < 600 && k < 20) ? f2bf(gw3[n * 20 + k]) : (ushort_t)0;
  }
  for (int i = tid; i < 608 * 224; i += np) {
    int n = i / 224, k = i - n * 224;
    ws[WS_W4 + i] = (n < 600 && k < 200) ? f2bf(gw4[n * 200 + k]) : (ushort_t)0;
  }
}

__global__ void prep_fac(const float* __restrict__ fw, ushort_t* __restrict__ ws) {
  int n = blockIdx.x;   // 64 rows
  int l = threadIdx.x;  // 64 lanes
  float ss = 0.f;
  for (int k = l; k < 200; k += 64) { float v = fw[n * 200 + k]; ss = fmaf(v, v, ss); }
  for (int off = 32; off; off >>= 1) ss += __shfl_down(ss, off, 64);
  ss = __shfl(ss, 0, 64);
  float inv = 1.0f / fmaxf(sqrtf(ss), 1e-12f);
  for (int k = l; k < 224; k += 64)
    ws[WS_W5 + n * 224 + k] = (k < 200) ? f2bf(fw[n * 200 + k] * inv) : (ushort_t)0;
}

__global__ __launch_bounds__(NT, 2) void decoder_kernel(
    const float* __restrict__ x, const float* __restrict__ h0, const float* __restrict__ eps,
    const float* __restrict__ gen_b_ih, const float* __restrict__ gen_b_hh,
    const float* __restrict__ con_b_ih, const float* __restrict__ con_b_hh,
    const float* __restrict__ co_w, const float* __restrict__ co_b,
    const ushort_t* __restrict__ ws, float* __restrict__ out)
{
  __shared__ __align__(16) unsigned char spool[POOLB];
  ushort_t* sA  = (ushort_t*)(spool + O_A);    // con_input [128][328]
  ushort_t* sGo = (ushort_t*)(spool + O_A);    // gen_state_old [128][216]
  ushort_t* sGn = (ushort_t*)(spool + O_GN);   // gen_state_new [128][216]
  ushort_t* sR2 = (ushort_t*)(spool + O_R2);   // con_state bf16 [128][136]
  ushort_t* sR3 = (ushort_t*)(spool + O_R3);   // gen_input [128][88] (cols 0..32)

  const int tid = threadIdx.x;
  const int rbase = blockIdx.x * RT;
  const int lane = tid & 63;
  const int w = tid >> 6;
  const int bn = lane & 15;           // frag row/col within 16
  const int kq = (lane >> 4) << 3;    // k offset of quarter-wave
  const int qrow = (lane >> 4) << 2;  // C/D row offset of quarter-wave

  // ---------------- ph1: stage con_input, con_state, factor; ext -> out
  #pragma unroll
  for (int it = 0; it < 16; ++it) {  // x[:,0:256] -> sA
    int idx = tid + it * NT;
    int r = idx >> 6, c4 = (idx & 63) << 2;
    f4 v = *(const f4*)&x[(size_t)(rbase + r) * XD + c4];
    *(us4*)&sA[r * STA + c4] = f2bf4(v);
  }
  {  // x[:,256:272] -> sR3 cols 4..20 (gen_input ext) + direct out store
    int r = tid >> 2, e = (tid & 3) << 2;
    f4 v = *(const f4*)&x[(size_t)(rbase + r) * XD + 256 + e];
    *(us4*)&sR3[r * STR3 + 4 + e] = f2bf4(v);
    *(f4*)&out[(size_t)(rbase + r) * HD + 340 + e] = v;
  }
  #pragma unroll
  for (int it = 0; it < 8; ++it) {  // h0[:,200:328] -> sR2 (con_state_old)
    int idx = tid + it * NT;
    int r = idx >> 5, c4 = (idx & 31) << 2;
    f4 v = *(const f4*)&h0[(size_t)(rbase + r) * HD + 200 + c4];
    *(us4*)&sR2[r * STH + c4] = f2bf4(v);
  }
  #pragma unroll
  for (int it = 0; it < 4; ++it) {  // h0[:,356:420] -> sA cols 256..320
    int idx = tid + it * NT;
    int r = idx >> 4, c4 = (idx & 15) << 2;
    f4 v = *(const f4*)&h0[(size_t)(rbase + r) * HD + 356 + c4];
    *(us4*)&sA[r * STA + 256 + c4] = f2bf4(v);
  }
  if (tid < 384) {  // zero sR3 cols 20..32 (gi K-pad)
    int r = tid / 3, q = (tid - (tid / 3) * 3) << 2;
    us4 z = {0, 0, 0, 0};
    *(us4*)&sR3[r * STR3 + 20 + q] = z;
  }
  __syncthreads();  // B1

  const int col = (w << 4) + bn;  // wave's con output column (0..127)

  // ---------------- ph2: con GEMMs (8 row-tiles/wave), batched prefetch
  f4 aR[8], aZ[8], aN[8], aHN[8];
  #pragma unroll
  for (int ri = 0; ri < 8; ++ri) {
    aR[ri] = (f4){0.f, 0.f, 0.f, 0.f};
    aZ[ri] = (f4){0.f, 0.f, 0.f, 0.f};
    aN[ri] = (f4){0.f, 0.f, 0.f, 0.f};
    aHN[ri] = (f4){0.f, 0.f, 0.f, 0.f};
  }
  {
    const ushort_t* W2 = ws + WS_W2;
    const ushort_t* W1 = ws + WS_W1;
    bf8 w2f[4][3], w1a[5][3];
    #pragma unroll
    for (int k = 0; k < 4; ++k) {
      w2f[k][0] = *(const bf8*)&W2[(size_t)(col) * 128 + k * 32 + kq];
      w2f[k][1] = *(const bf8*)&W2[(size_t)(128 + col) * 128 + k * 32 + kq];
      w2f[k][2] = *(const bf8*)&W2[(size_t)(256 + col) * 128 + k * 32 + kq];
    }
    #pragma unroll
    for (int k = 0; k < 5; ++k) {
      w1a[k][0] = *(const bf8*)&W1[(size_t)(col) * 320 + k * 32 + kq];
      w1a[k][1] = *(const bf8*)&W1[(size_t)(128 + col) * 320 + k * 32 + kq];
      w1a[k][2] = *(const bf8*)&W1[(size_t)(256 + col) * 320 + k * 32 + kq];
    }
    #pragma unroll
    for (int k = 0; k < 4; ++k) {  // gh (K=128)
      #pragma unroll
      for (int ri = 0; ri < 8; ++ri) {
        bf8 a = *(const bf8*)&sR2[(ri * 16 + bn) * STH + k * 32 + kq];
        aR[ri] = MFMA(a, w2f[k][0], aR[ri]);
        aZ[ri] = MFMA(a, w2f[k][1], aZ[ri]);
        aHN[ri] = MFMA(a, w2f[k][2], aHN[ri]);
      }
    }
    bf8 w1b[5][3];
    #pragma unroll
    for (int k = 0; k < 5; ++k) {
      w1b[k][0] = *(const bf8*)&W1[(size_t)(col) * 320 + (k + 5) * 32 + kq];
      w1b[k][1] = *(const bf8*)&W1[(size_t)(128 + col) * 320 + (k + 5) * 32 + kq];
      w1b[k][2] = *(const bf8*)&W1[(size_t)(256 + col) * 320 + (k + 5) * 32 + kq];
    }
    #pragma unroll
    for (int k = 0; k < 5; ++k) {  // gi batch A
      #pragma unroll
      for (int ri = 0; ri < 8; ++ri) {
        bf8 a = *(const bf8*)&sA[(ri * 16 + bn) * STA + k * 32 + kq];
        aR[ri] = MFMA(a, w1a[k][0], aR[ri]);
        aZ[ri] = MFMA(a, w1a[k][1], aZ[ri]);
        aN[ri] = MFMA(a, w1a[k][2], aN[ri]);
      }
    }
    #pragma unroll
    for (int k = 0; k < 5; ++k) {  // gi batch B
      #pragma unroll
      for (int ri = 0; ri < 8; ++ri) {
        bf8 a = *(const bf8*)&sA[(ri * 16 + bn) * STA + (k + 5) * 32 + kq];
        aR[ri] = MFMA(a, w1b[k][0], aR[ri]);
        aZ[ri] = MFMA(a, w1b[k][1], aZ[ri]);
        aN[ri] = MFMA(a, w1b[k][2], aN[ri]);
      }
    }
  }
  __syncthreads();  // B2 (sA + sR2 frag reads done)

  // ---------------- ph3: stage gen_state_old (over dead sA) || con epilogue
  for (int idx = tid; idx < 128 * 54; idx += NT) {
    int r = idx / 54, u = idx - (idx / 54) * 54;
    if (u < 50) {
      f4 v = *(const f4*)&h0[(size_t)(rbase + r) * HD + (u << 2)];
      *(us4*)&sGo[r * STG + (u << 2)] = f2bf4(v);
    } else {
      us4 z = {0, 0, 0, 0};
      *(us4*)&sGo[r * STG + 200 + ((u - 50) << 2)] = z;  // gh K-pad
    }
  }
  {
    float brr = con_b_ih[col] + con_b_hh[col];
    float brz = con_b_ih[128 + col] + con_b_hh[128 + col];
    float bin = con_b_ih[256 + col], bhn = con_b_hh[256 + col];
    #pragma unroll
    for (int ri = 0; ri < 8; ++ri) {
      #pragma unroll
      for (int j = 0; j < 4; ++j) {
        int row = ri * 16 + qrow + j;
        float hold = bf2f(sR2[row * STH + col]);
        float rr = sigf(aR[ri][j] + brr);
        float zz = sigf(aZ[ri][j] + brz);
        float nn = tanhf_(aN[ri][j] + bin + rr * (aHN[ri][j] + bhn));
        float hv = (1.f - zz) * nn + zz * hold;
        hv = fminf(fmaxf(hv, -5.f), 5.f);
        sR2[row * STH + col] = f2bf(hv);  // own (row,col) only: no race
        out[(size_t)(rbase + row) * HD + 200 + col] = hv;  // direct store
      }
    }
  }
  __syncthreads();  // B3

  // ---------------- ph4: co linear + reparam (f32 VALU; 128 rows x 8 cols)
  {
    int cn = tid & 7;
    #pragma unroll
    for (int half = 0; half < 2; ++half) {
      int crow = (tid >> 3) + half * 64;
      float acc = co_b[cn];
      #pragma unroll 8
      for (int k0 = 0; k0 < 128; k0 += 4) {
        f4 hv = bf2f4(*(const us4*)&sR2[crow * STH + k0]);
        f4 wv = *(const f4*)&co_w[cn * 128 + k0];
        acc = fmaf(hv.x, wv.x, acc);
        acc = fmaf(hv.y, wv.y, acc);
        acc = fmaf(hv.z, wv.z, acc);
        acc = fmaf(hv.w, wv.w, acc);
      }
      float lv = __shfl(acc, lane + 4, 64);  // partner lane holds logvar
      if (cn < 4) {
        float stdv = __expf(0.5f * lv);
        float ov = fmaf(stdv, eps[(size_t)(rbase + crow) * 4 + cn], acc);
        size_t orow = (size_t)(rbase + crow) * HD;
        out[orow + 328 + cn] = acc;
        out[orow + 332 + cn] = stdv;
        out[orow + 336 + cn] = ov;
        sR3[crow * STR3 + cn] = f2bf(ov);
      }
    }
  }
  __syncthreads();  // B4 (sR2 reads done; sGn may now overwrite its alias)

  // ---------------- ph6: gen GRU (13 col-tiles over 8 waves)
  {  // zero sGn K-pad cols 200..216
    int r = tid >> 2, q = (tid & 3) << 2;
    us4 z = {0, 0, 0, 0};
    *(us4*)&sGn[r * STG + 200 + q] = z;
  }
  {
    const ushort_t* W3 = ws + WS_W3;
    const ushort_t* W4 = ws + WS_W4;
    for (int t = w; t < 13; t += 8) {
      int c = (t << 4) + bn;  // output column (valid < 200)
      bf8 w3f[3], w4a[4][3];
      w3f[0] = *(const bf8*)&W3[(size_t)(c) * 32 + kq];
      w3f[1] = *(const bf8*)&W3[(size_t)(200 + c) * 32 + kq];
      w3f[2] = *(const bf8*)&W3[(size_t)(400 + c) * 32 + kq];
      #pragma unroll
      for (int k = 0; k < 4; ++k) {
        w4a[k][0] = *(const bf8*)&W4[(size_t)(c) * 224 + k * 32 + kq];
        w4a[k][1] = *(const bf8*)&W4[(size_t)(200 + c) * 224 + k * 32 + kq];
        w4a[k][2] = *(const bf8*)&W4[(size_t)(400 + c) * 224 + k * 32 + kq];
      }
      f4 gR[8], gZ[8], gN[8], gHN[8];
      #pragma unroll
      for (int ri = 0; ri < 8; ++ri) {
        gR[ri] = (f4){0.f, 0.f, 0.f, 0.f};
        gZ[ri] = (f4){0.f, 0.f, 0.f, 0.f};
        gN[ri] = (f4){0.f, 0.f, 0.f, 0.f};
        gHN[ri] = (f4){0.f, 0.f, 0.f, 0.f};
      }
      #pragma unroll
      for (int ri = 0; ri < 8; ++ri) {  // gi (K=32)
        bf8 a = *(const bf8*)&sR3[(ri * 16 + bn) * STR3 + kq];
        gR[ri] = MFMA(a, w3f[0], gR[ri]);
        gZ[ri] = MFMA(a, w3f[1], gZ[ri]);
        gN[ri] = MFMA(a, w3f[2], gN[ri]);
      }
      bf8 w4b[3][3];
      #pragma unroll
      for (int k = 0; k < 3; ++k) {
        w4b[k][0] = *(const bf8*)&W4[(size_t)(c) * 224 + (k + 4) * 32 + kq];
        w4b[k][1] = *(const bf8*)&W4[(size_t)(200 + c) * 224 + (k + 4) * 32 + kq];
        w4b[k][2] = *(const bf8*)&W4[(size_t)(400 + c) * 224 + (k + 4) * 32 + kq];
      }
      #pragma unroll
      for (int k = 0; k < 4; ++k) {  // gh batch A
        #pragma unroll
        for (int ri = 0; ri < 8; ++ri) {
          bf8 a = *(const bf8*)&sGo[(ri * 16 + bn) * STG + k * 32 + kq];
          gR[ri] = MFMA(a, w4a[k][0], gR[ri]);
          gZ[ri] = MFMA(a, w4a[k][1], gZ[ri]);
          gHN[ri] = MFMA(a, w4a[k][2], gHN[ri]);
        }
      }
      #pragma unroll
      for (int k = 0; k < 3; ++k) {  // gh batch B
        #pragma unroll
        for (int ri = 0; ri < 8; ++ri) {
          bf8 a = *(const bf8*)&sGo[(ri * 16 + bn) * STG + (k + 4) * 32 + kq];
          gR[ri] = MFMA(a, w4b[k][0], gR[ri]);
          gZ[ri] = MFMA(a, w4b[k][1], gZ[ri]);
          gHN[ri] = MFMA(a, w4b[k][2], gHN[ri]);
        }
      }
      if (c < 200) {
        float brr = gen_b_ih[c] + gen_b_hh[c];
        float brz = gen_b_ih[200 + c] + gen_b_hh[200 + c];
        float bin = gen_b_ih[400 + c], bhn = gen_b_hh[400 + c];
        #pragma unroll
        for (int ri = 0; ri < 8; ++ri) {
          #pragma unroll
          for (int j = 0; j < 4; ++j) {
            int row = ri * 16 + qrow + j;
            float hold = bf2f(sGo[row * STG + c]);
            float rr = sigf(gR[ri][j] + brr);
            float zz = sigf(gZ[ri][j] + brz);
            float nn = tanhf_(gN[ri][j] + bin + rr * (gHN[ri][j] + bhn));
            float hv = (1.f - zz) * nn + zz * hold;
            hv = fminf(fmaxf(hv, -5.f), 5.f);
            sGn[row * STG + c] = f2bf(hv);
            out[(size_t)(rbase + row) * HD + c] = hv;  // direct store
          }
        }
      }
    }
  }
  __syncthreads();  // B6

  // ---------------- ph7: factor = gen_state_new @ normed_fac^T -> out direct
  {
    const ushort_t* W5 = ws + WS_W5;
    #pragma unroll
    for (int job = 0; job < 4; ++job) {
      int ri = ((w & 3) << 1) + (job & 1);      // 0..7
      int ct = ((w >> 2) << 1) + (job >> 1);    // 0..3
      bf8 w5f[7];
      #pragma unroll
      for (int k = 0; k < 7; ++k)
        w5f[k] = *(const bf8*)&W5[(size_t)((ct << 4) + bn) * 224 + k * 32 + kq];
      f4 acc = (f4){0.f, 0.f, 0.f, 0.f};
      #pragma unroll
      for (int k = 0; k < 7; ++k) {
        bf8 a = *(const bf8*)&sGn[(ri * 16 + bn) * STG + k * 32 + kq];
        acc = MFMA(a, w5f[k], acc);
      }
      #pragma unroll
      for (int j = 0; j < 4; ++j) {
        int row = ri * 16 + qrow + j;
        out[(size_t)(rbase + row) * HD + 356 + (ct << 4) + bn] = acc[j];
      }
    }
  }
}

extern "C" void kernel_launch(void* const* d_in, const int* in_sizes, int n_in,
                              void* d_out, int out_size, void* d_ws, size_t ws_size,
                              hipStream_t stream) {
  const float* x        = (const float*)d_in[0];
  const float* h0       = (const float*)d_in[1];
  const float* eps      = (const float*)d_in[2];
  const float* gen_w_ih = (const float*)d_in[3];
  const float* gen_w_hh = (const float*)d_in[4];
  const float* gen_b_ih = (const float*)d_in[5];
  const float* gen_b_hh = (const float*)d_in[6];
  const float* con_w_ih = (const float*)d_in[7];
  const float* con_w_hh = (const float*)d_in[8];
  const float* con_b_ih = (const float*)d_in[9];
  const float* con_b_hh = (const float*)d_in[10];
  const float* co_w     = (const float*)d_in[11];
  const float* co_b     = (const float*)d_in[12];
  const float* fac_w    = (const float*)d_in[13];
  float* out = (float*)d_out;
  ushort_t* ws = (ushort_t*)d_ws;

  hipLaunchKernelGGL(prep_w, dim3(256), dim3(512), 0, stream,
                     con_w_ih, con_w_hh, gen_w_ih, gen_w_hh, ws);
  hipLaunchKernelGGL(prep_fac, dim3(64), dim3(64), 0, stream, fac_w, ws);

  int nrows = in_sizes[2] / 4;  // eps is (B,4)
  int grid = nrows / RT;        // 512
  hipLaunchKernelGGL(decoder_kernel, dim3(grid), dim3(NT), 0, stream,
                     x, h0, eps, gen_b_ih, gen_b_hh, con_b_ih, con_b_hh,
                     co_w, co_b, ws, out);
}

// Round 14
// 151.689 us; speedup vs baseline: 1.1774x; 1.0096x over previous
//
#include <hip/hip_runtime.h>
#include <math.h>

// DecoderCell fused kernel — Round 14: R13 base (direct epilogue stores, no
// flush phases) with K-loops DE-UNROLLED (#pragma unroll 1). Theory: the
// occupancy-/ILP-invariant ~70% stall is instruction-fetch (fully-unrolled
// ~50KB hot code streams through 32KB I$; every wave pays the miss chain).
// Loop bodies (3 B-frag loads + 8 ds_read + 24 MFMA) become I$-resident.

#define NT 512
#define RT 128
#define XD 272
#define HD 420

typedef unsigned short ushort_t;
typedef __attribute__((ext_vector_type(8))) short bf8;
typedef __attribute__((ext_vector_type(4))) float f4;
typedef __attribute__((ext_vector_type(4))) unsigned short us4;

// ws layout (bf16 element offsets)
#define WS_W1 0         // con_w_ih [384][320]
#define WS_W2 122880    // con_w_hh [384][128]
#define WS_W3 172032    // gen_w_ih [608][32]  (K 20->32 pad, rows 600-607 zero)
#define WS_W4 191488    // gen_w_hh [608][224] (K 200->224 pad, rows 600-607 zero)
#define WS_W5 327680    // normed fac_w [64][224] (K pad zero)

#define STA 328
#define STG 216
#define STH 136
#define STR3 88

#define O_A   0        // sA [128][328] = 83,968 ; later sGo [128][216]=55,296
#define O_GN  55296    // sGn [128][216] = 55,296
#define O_R2  83968    // sR2 [128][136] = 34,816
#define O_R3  118784   // sR3 [128][88]  = 22,528
#define POOLB 141312

__device__ __forceinline__ ushort_t f2bf(float f) {
  union { float f; unsigned u; } v; v.f = f;
  unsigned r = v.u + 0x7FFFu + ((v.u >> 16) & 1u);
  return (ushort_t)(r >> 16);
}
__device__ __forceinline__ float bf2f(ushort_t u) {
  union { unsigned u; float f; } v; v.u = ((unsigned)u) << 16; return v.f;
}
__device__ __forceinline__ us4 f2bf4(f4 v) {
  us4 b; b.x = f2bf(v.x); b.y = f2bf(v.y); b.z = f2bf(v.z); b.w = f2bf(v.w); return b;
}
__device__ __forceinline__ f4 bf2f4(us4 b) {
  f4 v; v.x = bf2f(b.x); v.y = bf2f(b.y); v.z = bf2f(b.z); v.w = bf2f(b.w); return v;
}
__device__ __forceinline__ float rcpf(float x) { return __builtin_amdgcn_rcpf(x); }
__device__ __forceinline__ float sigf(float x) { return rcpf(1.0f + __expf(-x)); }
__device__ __forceinline__ float tanhf_(float x) {
  return 1.0f - 2.0f * rcpf(1.0f + __expf(2.0f * x));
}

#define MFMA(a, b, c) __builtin_amdgcn_mfma_f32_16x16x32_bf16((a), (b), (c), 0, 0, 0)

__global__ void prep_w(const float* __restrict__ cw1, const float* __restrict__ cw2,
                       const float* __restrict__ gw3, const float* __restrict__ gw4,
                       ushort_t* __restrict__ ws) {
  int tid = blockIdx.x * blockDim.x + threadIdx.x;
  int np = gridDim.x * blockDim.x;
  for (int i = tid; i < 384 * 320; i += np) ws[WS_W1 + i] = f2bf(cw1[i]);
  for (int i = tid; i < 384 * 128; i += np) ws[WS_W2 + i] = f2bf(cw2[i]);
  for (int i = tid; i < 608 * 32; i += np) {
    int n = i >> 5, k = i & 31;
    ws[WS_W3 + i] = (n < 600 && k < 20) ? f2bf(gw3[n * 20 + k]) : (ushort_t)0;
  }
  for (int i = tid; i < 608 * 224; i += np) {
    int n = i / 224, k = i - n * 224;
    ws[WS_W4 + i] = (n < 600 && k < 200) ? f2bf(gw4[n * 200 + k]) : (ushort_t)0;
  }
}

__global__ void prep_fac(const float* __restrict__ fw, ushort_t* __restrict__ ws) {
  int n = blockIdx.x;   // 64 rows
  int l = threadIdx.x;  // 64 lanes
  float ss = 0.f;
  for (int k = l; k < 200; k += 64) { float v = fw[n * 200 + k]; ss = fmaf(v, v, ss); }
  for (int off = 32; off; off >>= 1) ss += __shfl_down(ss, off, 64);
  ss = __shfl(ss, 0, 64);
  float inv = 1.0f / fmaxf(sqrtf(ss), 1e-12f);
  for (int k = l; k < 224; k += 64)
    ws[WS_W5 + n * 224 + k] = (k < 200) ? f2bf(fw[n * 200 + k] * inv) : (ushort_t)0;
}

__global__ __launch_bounds__(NT, 2) void decoder_kernel(
    const float* __restrict__ x, const float* __restrict__ h0, const float* __restrict__ eps,
    const float* __restrict__ gen_b_ih, const float* __restrict__ gen_b_hh,
    const float* __restrict__ con_b_ih, const float* __restrict__ con_b_hh,
    const float* __restrict__ co_w, const float* __restrict__ co_b,
    const ushort_t* __restrict__ ws, float* __restrict__ out)
{
  __shared__ __align__(16) unsigned char spool[POOLB];
  ushort_t* sA  = (ushort_t*)(spool + O_A);    // con_input [128][328]
  ushort_t* sGo = (ushort_t*)(spool + O_A);    // gen_state_old [128][216]
  ushort_t* sGn = (ushort_t*)(spool + O_GN);   // gen_state_new [128][216]
  ushort_t* sR2 = (ushort_t*)(spool + O_R2);   // con_state bf16 [128][136]
  ushort_t* sR3 = (ushort_t*)(spool + O_R3);   // gen_input [128][88] (cols 0..32)

  const int tid = threadIdx.x;
  const int rbase = blockIdx.x * RT;
  const int lane = tid & 63;
  const int w = tid >> 6;
  const int bn = lane & 15;           // frag row/col within 16
  const int kq = (lane >> 4) << 3;    // k offset of quarter-wave
  const int qrow = (lane >> 4) << 2;  // C/D row offset of quarter-wave

  // ---------------- ph1: stage con_input, con_state, factor; ext -> out
  #pragma unroll
  for (int it = 0; it < 16; ++it) {  // x[:,0:256] -> sA
    int idx = tid + it * NT;
    int r = idx >> 6, c4 = (idx & 63) << 2;
    f4 v = *(const f4*)&x[(size_t)(rbase + r) * XD + c4];
    *(us4*)&sA[r * STA + c4] = f2bf4(v);
  }
  {  // x[:,256:272] -> sR3 cols 4..20 (gen_input ext) + direct out store
    int r = tid >> 2, e = (tid & 3) << 2;
    f4 v = *(const f4*)&x[(size_t)(rbase + r) * XD + 256 + e];
    *(us4*)&sR3[r * STR3 + 4 + e] = f2bf4(v);
    *(f4*)&out[(size_t)(rbase + r) * HD + 340 + e] = v;
  }
  #pragma unroll
  for (int it = 0; it < 8; ++it) {  // h0[:,200:328] -> sR2 (con_state_old)
    int idx = tid + it * NT;
    int r = idx >> 5, c4 = (idx & 31) << 2;
    f4 v = *(const f4*)&h0[(size_t)(rbase + r) * HD + 200 + c4];
    *(us4*)&sR2[r * STH + c4] = f2bf4(v);
  }
  #pragma unroll
  for (int it = 0; it < 4; ++it) {  // h0[:,356:420] -> sA cols 256..320
    int idx = tid + it * NT;
    int r = idx >> 4, c4 = (idx & 15) << 2;
    f4 v = *(const f4*)&h0[(size_t)(rbase + r) * HD + 356 + c4];
    *(us4*)&sA[r * STA + 256 + c4] = f2bf4(v);
  }
  if (tid < 384) {  // zero sR3 cols 20..32 (gi K-pad)
    int r = tid / 3, q = (tid - (tid / 3) * 3) << 2;
    us4 z = {0, 0, 0, 0};
    *(us4*)&sR3[r * STR3 + 20 + q] = z;
  }
  __syncthreads();  // B1

  const int col = (w << 4) + bn;  // wave's con output column (0..127)

  // ---------------- ph2: con GEMMs (8 row-tiles/wave), I$-resident loops
  f4 aR[8], aZ[8], aN[8], aHN[8];
  #pragma unroll
  for (int ri = 0; ri < 8; ++ri) {
    aR[ri] = (f4){0.f, 0.f, 0.f, 0.f};
    aZ[ri] = (f4){0.f, 0.f, 0.f, 0.f};
    aN[ri] = (f4){0.f, 0.f, 0.f, 0.f};
    aHN[ri] = (f4){0.f, 0.f, 0.f, 0.f};
  }
  {
    const ushort_t* W2 = ws + WS_W2;
    #pragma unroll 1
    for (int k0 = 0; k0 < 128; k0 += 32) {  // gh (K=128)
      bf8 b0 = *(const bf8*)&W2[(size_t)(col) * 128 + k0 + kq];
      bf8 b1 = *(const bf8*)&W2[(size_t)(128 + col) * 128 + k0 + kq];
      bf8 bm = *(const bf8*)&W2[(size_t)(256 + col) * 128 + k0 + kq];
      #pragma unroll
      for (int ri = 0; ri < 8; ++ri) {
        bf8 a = *(const bf8*)&sR2[(ri * 16 + bn) * STH + k0 + kq];
        aR[ri] = MFMA(a, b0, aR[ri]);
        aZ[ri] = MFMA(a, b1, aZ[ri]);
        aHN[ri] = MFMA(a, bm, aHN[ri]);
      }
    }
    const ushort_t* W1 = ws + WS_W1;
    #pragma unroll 1
    for (int k0 = 0; k0 < 320; k0 += 32) {  // gi (K=320)
      bf8 b0 = *(const bf8*)&W1[(size_t)(col) * 320 + k0 + kq];
      bf8 b1 = *(const bf8*)&W1[(size_t)(128 + col) * 320 + k0 + kq];
      bf8 bm = *(const bf8*)&W1[(size_t)(256 + col) * 320 + k0 + kq];
      #pragma unroll
      for (int ri = 0; ri < 8; ++ri) {
        bf8 a = *(const bf8*)&sA[(ri * 16 + bn) * STA + k0 + kq];
        aR[ri] = MFMA(a, b0, aR[ri]);
        aZ[ri] = MFMA(a, b1, aZ[ri]);
        aN[ri] = MFMA(a, bm, aN[ri]);
      }
    }
  }
  __syncthreads();  // B2 (sA + sR2 frag reads done)

  // ---------------- ph3: stage gen_state_old (over dead sA) || con epilogue
  #pragma unroll 1
  for (int idx = tid; idx < 128 * 54; idx += NT) {
    int r = idx / 54, u = idx - (idx / 54) * 54;
    if (u < 50) {
      f4 v = *(const f4*)&h0[(size_t)(rbase + r) * HD + (u << 2)];
      *(us4*)&sGo[r * STG + (u << 2)] = f2bf4(v);
    } else {
      us4 z = {0, 0, 0, 0};
      *(us4*)&sGo[r * STG + 200 + ((u - 50) << 2)] = z;  // gh K-pad
    }
  }
  {
    float brr = con_b_ih[col] + con_b_hh[col];
    float brz = con_b_ih[128 + col] + con_b_hh[128 + col];
    float bin = con_b_ih[256 + col], bhn = con_b_hh[256 + col];
    #pragma unroll
    for (int ri = 0; ri < 8; ++ri) {
      #pragma unroll
      for (int j = 0; j < 4; ++j) {
        int row = ri * 16 + qrow + j;
        float hold = bf2f(sR2[row * STH + col]);
        float rr = sigf(aR[ri][j] + brr);
        float zz = sigf(aZ[ri][j] + brz);
        float nn = tanhf_(aN[ri][j] + bin + rr * (aHN[ri][j] + bhn));
        float hv = (1.f - zz) * nn + zz * hold;
        hv = fminf(fmaxf(hv, -5.f), 5.f);
        sR2[row * STH + col] = f2bf(hv);  // own (row,col) only: no race
        out[(size_t)(rbase + row) * HD + 200 + col] = hv;  // direct store
      }
    }
  }
  __syncthreads();  // B3

  // ---------------- ph4: co linear + reparam (f32 VALU; 128 rows x 8 cols)
  {
    int cn = tid & 7;
    #pragma unroll
    for (int half = 0; half < 2; ++half) {
      int crow = (tid >> 3) + half * 64;
      float acc = co_b[cn];
      #pragma unroll 8
      for (int k0 = 0; k0 < 128; k0 += 4) {
        f4 hv = bf2f4(*(const us4*)&sR2[crow * STH + k0]);
        f4 wv = *(const f4*)&co_w[cn * 128 + k0];
        acc = fmaf(hv.x, wv.x, acc);
        acc = fmaf(hv.y, wv.y, acc);
        acc = fmaf(hv.z, wv.z, acc);
        acc = fmaf(hv.w, wv.w, acc);
      }
      float lv = __shfl(acc, lane + 4, 64);  // partner lane holds logvar
      if (cn < 4) {
        float stdv = __expf(0.5f * lv);
        float ov = fmaf(stdv, eps[(size_t)(rbase + crow) * 4 + cn], acc);
        size_t orow = (size_t)(rbase + crow) * HD;
        out[orow + 328 + cn] = acc;
        out[orow + 332 + cn] = stdv;
        out[orow + 336 + cn] = ov;
        sR3[crow * STR3 + cn] = f2bf(ov);
      }
    }
  }
  __syncthreads();  // B4 (sR2 reads done; sGn may now overwrite its alias)

  // ---------------- ph6: gen GRU (13 col-tiles over 8 waves)
  {  // zero sGn K-pad cols 200..216
    int r = tid >> 2, q = (tid & 3) << 2;
    us4 z = {0, 0, 0, 0};
    *(us4*)&sGn[r * STG + 200 + q] = z;
  }
  {
    const ushort_t* W3 = ws + WS_W3;
    const ushort_t* W4 = ws + WS_W4;
    #pragma unroll 1
    for (int t = w; t < 13; t += 8) {
      int c = (t << 4) + bn;  // output column (valid < 200)
      f4 gR[8], gZ[8], gN[8], gHN[8];
      #pragma unroll
      for (int ri = 0; ri < 8; ++ri) {
        gR[ri] = (f4){0.f, 0.f, 0.f, 0.f};
        gZ[ri] = (f4){0.f, 0.f, 0.f, 0.f};
        gN[ri] = (f4){0.f, 0.f, 0.f, 0.f};
        gHN[ri] = (f4){0.f, 0.f, 0.f, 0.f};
      }
      {  // gi (K=32)
        bf8 b0 = *(const bf8*)&W3[(size_t)(c) * 32 + kq];
        bf8 b1 = *(const bf8*)&W3[(size_t)(200 + c) * 32 + kq];
        bf8 bm = *(const bf8*)&W3[(size_t)(400 + c) * 32 + kq];
        #pragma unroll
        for (int ri = 0; ri < 8; ++ri) {
          bf8 a = *(const bf8*)&sR3[(ri * 16 + bn) * STR3 + kq];
          gR[ri] = MFMA(a, b0, gR[ri]);
          gZ[ri] = MFMA(a, b1, gZ[ri]);
          gN[ri] = MFMA(a, bm, gN[ri]);
        }
      }
      #pragma unroll 1
      for (int k0 = 0; k0 < 224; k0 += 32) {  // gh (K=200 padded)
        bf8 b0 = *(const bf8*)&W4[(size_t)(c) * 224 + k0 + kq];
        bf8 b1 = *(const bf8*)&W4[(size_t)(200 + c) * 224 + k0 + kq];
        bf8 bm = *(const bf8*)&W4[(size_t)(400 + c) * 224 + k0 + kq];
        #pragma unroll
        for (int ri = 0; ri < 8; ++ri) {
          bf8 a = *(const bf8*)&sGo[(ri * 16 + bn) * STG + k0 + kq];
          gR[ri] = MFMA(a, b0, gR[ri]);
          gZ[ri] = MFMA(a, b1, gZ[ri]);
          gHN[ri] = MFMA(a, bm, gHN[ri]);
        }
      }
      if (c < 200) {
        float brr = gen_b_ih[c] + gen_b_hh[c];
        float brz = gen_b_ih[200 + c] + gen_b_hh[200 + c];
        float bin = gen_b_ih[400 + c], bhn = gen_b_hh[400 + c];
        #pragma unroll
        for (int ri = 0; ri < 8; ++ri) {
          #pragma unroll
          for (int j = 0; j < 4; ++j) {
            int row = ri * 16 + qrow + j;
            float hold = bf2f(sGo[row * STG + c]);
            float rr = sigf(gR[ri][j] + brr);
            float zz = sigf(gZ[ri][j] + brz);
            float nn = tanhf_(gN[ri][j] + bin + rr * (gHN[ri][j] + bhn));
            float hv = (1.f - zz) * nn + zz * hold;
            hv = fminf(fmaxf(hv, -5.f), 5.f);
            sGn[row * STG + c] = f2bf(hv);
            out[(size_t)(rbase + row) * HD + c] = hv;  // direct store
          }
        }
      }
    }
  }
  __syncthreads();  // B6

  // ---------------- ph7: factor = gen_state_new @ normed_fac^T -> out direct
  {
    const ushort_t* W5 = ws + WS_W5;
    #pragma unroll 1
    for (int job = 0; job < 4; ++job) {
      int ri = ((w & 3) << 1) + (job & 1);      // 0..7
      int ct = ((w >> 2) << 1) + (job >> 1);    // 0..3
      bf8 w5f[7];
      #pragma unroll
      for (int k = 0; k < 7; ++k)
        w5f[k] = *(const bf8*)&W5[(size_t)((ct << 4) + bn) * 224 + k * 32 + kq];
      f4 acc = (f4){0.f, 0.f, 0.f, 0.f};
      #pragma unroll
      for (int k = 0; k < 7; ++k) {
        bf8 a = *(const bf8*)&sGn[(ri * 16 + bn) * STG + k * 32 + kq];
        acc = MFMA(a, w5f[k], acc);
      }
      #pragma unroll
      for (int j = 0; j < 4; ++j) {
        int row = ri * 16 + qrow + j;
        out[(size_t)(rbase + row) * HD + 356 + (ct << 4) + bn] = acc[j];
      }
    }
  }
}

extern "C" void kernel_launch(void* const* d_in, const int* in_sizes, int n_in,
                              void* d_out, int out_size, void* d_ws, size_t ws_size,
                              hipStream_t stream) {
  const float* x        = (const float*)d_in[0];
  const float* h0       = (const float*)d_in[1];
  const float* eps      = (const float*)d_in[2];
  const float* gen_w_ih = (const float*)d_in[3];
  const float* gen_w_hh = (const float*)d_in[4];
  const float* gen_b_ih = (const float*)d_in[5];
  const float* gen_b_hh = (const float*)d_in[6];
  const float* con_w_ih = (const float*)d_in[7];
  const float* con_w_hh = (const float*)d_in[8];
  const float* con_b_ih = (const float*)d_in[9];
  const float* con_b_hh = (const float*)d_in[10];
  const float* co_w     = (const float*)d_in[11];
  const float* co_b     = (const float*)d_in[12];
  const float* fac_w    = (const float*)d_in[13];
  float* out = (float*)d_out;
  ushort_t* ws = (ushort_t*)d_ws;

  hipLaunchKernelGGL(prep_w, dim3(256), dim3(512), 0, stream,
                     con_w_ih, con_w_hh, gen_w_ih, gen_w_hh, ws);
  hipLaunchKernelGGL(prep_fac, dim3(64), dim3(64), 0, stream, fac_w, ws);

  int nrows = in_sizes[2] / 4;  // eps is (B,4)
  int grid = nrows / RT;        // 512
  hipLaunchKernelGGL(decoder_kernel, dim3(grid), dim3(NT), 0, stream,
                     x, h0, eps, gen_b_ih, gen_b_hh, con_b_ih, con_b_hh,
                     co_w, co_b, ws, out);
}